// Round 5
// baseline (201.321 us; speedup 1.0000x reference)
//
#include <hip/hip_runtime.h>
#include <math.h>

// Problem constants (from reference setup_inputs)
constexpr int B = 64;
constexpr int T = 1024;
constexpr int C = 128;
constexpr int L = 256;
constexpr int S = 2 * L + 1;     // 513 extended states
constexpr int TRB = 2048;        // transpose blocks (blockIdx >= B)
constexpr int N4 = T * B * C / 4;

template <int N> struct IC { static constexpr int value = N; };

// Fused kernel:
//   blocks [0, B)      : CTC forward, one 64-lane wave per batch element.
//                        Linear-prob domain, alpha in registers, 4-step
//                        halo-blocked wedge. Label probabilities come from
//                        DIRECT scattered global loads (own 4 columns per
//                        lane), prefetched 3 groups ahead in a 4-slot
//                        register ring (vmcnt: 6-bit, no saturation). Halo
//                        label-probs via shfl_up of the own ring (they ARE
//                        the previous lane's values). Blank column staged
//                        once in LDS. This removes R4's 32 random-address
//                        LDS gathers/group whose slow completion + the
//                        4-bit lgkmcnt limit (max 15) collapsed the
//                        pipeline (1125 cyc/group, 1.5M conflict cycles).
//   blocks [B, B+TRB)  : log + [B,T,C] -> [T,B,C] transpose (Output 0).
__global__ __launch_bounds__(64, 1) void ctc_fused(
    const float* __restrict__ yp,    // [B,T,C] probabilities
    const int*   __restrict__ yt,    // [B,L]
    const int*   __restrict__ il_,   // [B]
    const int*   __restrict__ ll_,   // [B]
    float* __restrict__ out_log,     // [T,B,C]
    float* __restrict__ out_loss)    // scalar, pre-zeroed; atomic mean
{
    if (blockIdx.x >= B) {
        // ---- transpose + log path (memory-bound, runs on idle CUs) ----
        int gid = (blockIdx.x - B) * 64 + threadIdx.x;
        const float4* in4 = (const float4*)yp;
        float4* o4 = (float4*)out_log;
        for (int i = gid; i < N4; i += TRB * 64) {
            int c4 = i & 31;
            int tb = i >> 5;
            int bb = tb & 63;
            int tt = tb >> 6;
            float4 v = in4[(bb * T + tt) * 32 + c4];
            float4 r;
            r.x = __logf(v.x); r.y = __logf(v.y);
            r.z = __logf(v.z); r.w = __logf(v.w);
            o4[i] = r;
        }
        return;
    }

    // ---- CTC forward path ----
    const int b    = blockIdx.x;
    const int lane = threadIdx.x;

    __shared__ float blanks[T];   // p[t][0] for all t (4 KB)
    __shared__ float afin[S];     // final alphas for loss extraction

    int il = il_[b]; il = min(max(il, 1), T);
    int ll = ll_[b]; ll = min(max(ll, 1), L);
    const float* yb = yp + (size_t)b * T * C;   // [T,C] slice for this b

    // Labels. Lane owns states s = 8*lane-8+i in w[i], i in [0,16];
    // persistent alphas in w[8..16] (states 8l..8l+8), w[0..7] is the halo.
    int4 y4  = *(const int4*)(yt + b * L + 4 * lane);
    int  po  = lane ? 4 * lane - 4 : 0;
    int4 py4 = *(const int4*)(yt + b * L + po);              // prev lane's labels
    int  ppw = yt[b * L + (lane >= 2 ? 4 * lane - 5 : 0)];

    int lab[8]   = {py4.x, py4.y, py4.z, py4.w, y4.x, y4.y, y4.z, y4.w};
    int labm1[8] = {ppw,   py4.x, py4.y, py4.z, py4.w, y4.x, y4.y, y4.z};
    float skf[8];
    #pragma unroll
    for (int k = 0; k < 8; ++k)
        skf[k] = ((4 * lane + k >= 5) && (lab[k] != labm1[k])) ? 1.f : 0.f;

    const int c0 = y4.x, c1 = y4.y, c2 = y4.z, c3 = y4.w;  // own columns

    // Blank column -> LDS (one-time; strided scattered reads, off hot path).
    #pragma unroll
    for (int i = 0; i < T / 64; ++i)
        blanks[i * 64 + lane] = yb[(size_t)(i * 64 + lane) * C];

    float p00 = yb[0];
    float p0l = yb[c0];

    // Own-label probability ring: slot (g & 3) holds rows 4g+1..4g+4.
    float gvL[4][4][4];
    auto ldgrp = [&](auto Sc, int g) {
        constexpr int SL = decltype(Sc)::value;
        #pragma unroll
        for (int j = 0; j < 4; ++j) {
            int r = 4 * g + 1 + j; r = r > T - 1 ? T - 1 : r;
            const float* rp = yb + (size_t)r * C;
            gvL[SL][j][0] = rp[c0]; gvL[SL][j][1] = rp[c1];
            gvL[SL][j][2] = rp[c2]; gvL[SL][j][3] = rp[c3];
        }
    };
    ldgrp(IC<0>{}, 0); ldgrp(IC<1>{}, 1); ldgrp(IC<2>{}, 2);   // warm 3 groups

    float w[17];
    #pragma unroll
    for (int i = 0; i < 17; ++i) w[i] = 0.f;
    if (lane == 0) { w[8] = p00; w[9] = p0l; }   // alpha0: states 0,1

    auto halo = [&]() {
        #pragma unroll
        for (int k = 0; k < 8; ++k) {
            float h = __shfl_up(w[8 + k], 1);
            w[k] = lane ? h : 0.f;
        }
    };
    halo();

    float ls = 0.f;        // accumulated log2 scale (exact integers)
    float m_meas = 1.0f;   // pipelined rescale max (lags ~8 steps)
    int t0 = 0;

    // One 4-step group, ring phase P (compile-time).
    auto group = [&](auto Pc) {
        constexpr int P  = decltype(Pc)::value;
        constexpr int PN = (P + 3) & 3;
        // 1) prefetch rows t0+13..t0+16 (group g+3) into slot PN — VMEM pipe,
        //    ~3 group-times (~900 cyc) of slack.
        {
            #pragma unroll
            for (int j = 0; j < 4; ++j) {
                int r = t0 + 13 + j; r = r > T - 1 ? T - 1 : r;
                const float* rp = yb + (size_t)r * C;
                gvL[PN][j][0] = rp[c0]; gvL[PN][j][1] = rp[c1];
                gvL[PN][j][2] = rp[c2]; gvL[PN][j][3] = rp[c3];
            }
        }
        // 2) halo label-probs = previous lane's own values (12 shfls).
        float gvp1[4], gvp2[4], gvp3[4];
        #pragma unroll
        for (int j = 0; j < 4; ++j) {
            gvp1[j] = __shfl_up(gvL[P][j][1], 1);
            gvp2[j] = __shfl_up(gvL[P][j][2], 1);
            gvp3[j] = __shfl_up(gvL[P][j][3], 1);
        }
        // 3) blank probs (broadcast LDS reads, conflict-free).
        float gb[4];
        #pragma unroll
        for (int j = 0; j < 4; ++j) gb[j] = blanks[t0 + 1 + j];
        // 4) wedge: 4 halo-blocked steps, in-place descending.
        #pragma unroll
        for (int j = 0; j < 4; ++j) {
            #pragma unroll
            for (int i = 16; i >= 2 * (j + 1); --i) {
                float acc = w[i] + w[i - 1];
                float g;
                if (i & 1) {
                    constexpr_int:;
                    const int k = (i - 1) >> 1;
                    acc = fmaf(skf[k], w[i - 2], acc);
                    g = (k >= 4) ? gvL[P][j][k - 4]
                                 : (k == 1 ? gvp1[j] : (k == 2 ? gvp2[j] : gvp3[j]));
                } else {
                    g = gb[j];
                }
                w[i] = acc * g;
            }
        }
        t0 += 4;
    };

    // Exact power-of-2 rescale, centered at 2^96.
    auto rescale = [&](float mm) {
        int eb = (__float_as_int(mm) >> 23) & 0xff;
        int sh = 350 - eb;
        sh = sh > 254 ? 254 : (sh < 1 ? 1 : sh);
        float inv = __int_as_float(sh << 23);
        #pragma unroll
        for (int i = 8; i < 17; ++i) w[i] *= inv;
        ls -= (float)(sh - 127);
    };
    auto maxw = [&]() {
        return fmaxf(fmaxf(fmaxf(w[8], w[9]), fmaxf(w[10], w[11])),
                     fmaxf(fmaxf(w[12], w[13]),
                           fmaxf(fmaxf(w[14], w[15]), w[16])));
    };

    const int full_end = ((il - 1) >> 2) << 2;

    // Main body: 4 groups (16 steps) per iteration; ring phases static.
    while (t0 + 16 <= full_end) {
        float mm = m_meas;   // butterfly pipelined across 2 groups
        mm = fmaxf(mm, __shfl_xor(mm, 1));
        mm = fmaxf(mm, __shfl_xor(mm, 2));
        mm = fmaxf(mm, __shfl_xor(mm, 4));
        group(IC<0>{});
        halo();
        mm = fmaxf(mm, __shfl_xor(mm, 8));
        mm = fmaxf(mm, __shfl_xor(mm, 16));
        mm = fmaxf(mm, __shfl_xor(mm, 32));
        group(IC<1>{});
        rescale(mm);
        m_meas = maxw();
        halo();

        float m2 = m_meas;
        m2 = fmaxf(m2, __shfl_xor(m2, 1));
        m2 = fmaxf(m2, __shfl_xor(m2, 2));
        m2 = fmaxf(m2, __shfl_xor(m2, 4));
        group(IC<2>{});
        halo();
        m2 = fmaxf(m2, __shfl_xor(m2, 8));
        m2 = fmaxf(m2, __shfl_xor(m2, 16));
        m2 = fmaxf(m2, __shfl_xor(m2, 32));
        group(IC<3>{});
        rescale(m2);
        m_meas = maxw();
        halo();
    }

    // Peeled groups (0..3), each with a fresh (non-pipelined) rescale.
    auto fresh_rescale = [&]() {
        float mm = maxw();
        #pragma unroll
        for (int off = 1; off < 64; off <<= 1) mm = fmaxf(mm, __shfl_xor(mm, off));
        rescale(mm);
    };
    if (t0 + 4 <= full_end) { group(IC<0>{}); fresh_rescale(); halo(); }
    if (t0 + 4 <= full_end) { group(IC<1>{}); fresh_rescale(); halo(); }
    if (t0 + 4 <= full_end) { group(IC<2>{}); }

    // Tail: rows full_end+1 .. il-1 (0..3 steps) use ring slot (full_end/4)&3.
    const int ph = (full_end >> 2) & 3;
    float tg[3][4];
    switch (ph) {
    case 0:
        #pragma unroll
        for (int j = 0; j < 3; ++j) { tg[j][0]=gvL[0][j][0]; tg[j][1]=gvL[0][j][1]; tg[j][2]=gvL[0][j][2]; tg[j][3]=gvL[0][j][3]; }
        break;
    case 1:
        #pragma unroll
        for (int j = 0; j < 3; ++j) { tg[j][0]=gvL[1][j][0]; tg[j][1]=gvL[1][j][1]; tg[j][2]=gvL[1][j][2]; tg[j][3]=gvL[1][j][3]; }
        break;
    case 2:
        #pragma unroll
        for (int j = 0; j < 3; ++j) { tg[j][0]=gvL[2][j][0]; tg[j][1]=gvL[2][j][1]; tg[j][2]=gvL[2][j][2]; tg[j][3]=gvL[2][j][3]; }
        break;
    default:
        #pragma unroll
        for (int j = 0; j < 3; ++j) { tg[j][0]=gvL[3][j][0]; tg[j][1]=gvL[3][j][1]; tg[j][2]=gvL[3][j][2]; tg[j][3]=gvL[3][j][3]; }
        break;
    }
    #pragma unroll
    for (int j = 0; j < 3; ++j) {
        int r = full_end + 1 + j;
        if (r < il) {   // uniform branch (il, r wave-uniform)
            float hh = __shfl_up(w[15], 1); if (lane == 0) hh = 0.f;
            float gb = blanks[r];
            float n8  = (w[8] + hh) * gb;
            float n9  = fmaf(skf[4], hh,    w[9]  + w[8])  * tg[j][0];
            float n10 = (w[10] + w[9])  * gb;
            float n11 = fmaf(skf[5], w[9],  w[11] + w[10]) * tg[j][1];
            float n12 = (w[12] + w[11]) * gb;
            float n13 = fmaf(skf[6], w[11], w[13] + w[12]) * tg[j][2];
            float n14 = (w[14] + w[13]) * gb;
            float n15 = fmaf(skf[7], w[13], w[15] + w[14]) * tg[j][3];
            float n16 = (w[16] + w[15]) * gb;
            w[8] = n8;  w[9] = n9;  w[10] = n10; w[11] = n11; w[12] = n12;
            w[13] = n13; w[14] = n14; w[15] = n15; w[16] = n16;
        }
    }

    // Loss: -ln(alpha[2ll-1] + alpha[2ll]) with accumulated scale.
    #pragma unroll
    for (int k = 0; k < 8; ++k) afin[8 * lane + k] = w[8 + k];
    if (lane == 63) afin[512] = w[16];
    __syncthreads();
    if (lane == 0) {
        float e1 = afin[2 * ll - 1];
        float e2 = afin[2 * ll];
        float sum = fmaxf(e1 + e2, 1e-37f);
        float loss = -(__log2f(sum) + ls) * 0.6931471805599453f;  // nats
        atomicAdd(out_loss, loss * (1.0f / (float)B));
    }
}

extern "C" void kernel_launch(void* const* d_in, const int* in_sizes, int n_in,
                              void* d_out, int out_size, void* d_ws, size_t ws_size,
                              hipStream_t stream) {
    const int*   y_true = (const int*)d_in[0];
    const float* y_pred = (const float*)d_in[1];
    const int*   in_len = (const int*)d_in[2];
    const int*   lb_len = (const int*)d_in[3];

    float* out_log  = (float*)d_out;                      // [T,B,C]
    float* out_loss = (float*)d_out + (size_t)T * B * C;  // scalar

    hipMemsetAsync(out_loss, 0, sizeof(float), stream);
    ctc_fused<<<B + TRB, 64, 0, stream>>>(y_pred, y_true, in_len, lb_len,
                                          out_log, out_loss);
}

// Round 6
// 197.877 us; speedup vs baseline: 1.0174x; 1.0174x over previous
//
#include <hip/hip_runtime.h>
#include <math.h>

// Problem constants (from reference setup_inputs)
constexpr int B = 64;
constexpr int T = 1024;
constexpr int C = 128;
constexpr int L = 256;
constexpr int S = 2 * L + 1;     // 513 extended states
constexpr int TRB = 2048;        // transpose blocks (blockIdx >= B)
constexpr int N4 = T * B * C / 4;

template <int N> struct IC { static constexpr int value = N; };

// shfl_up by 1 lane as pure VALU (DPP wave_shr:1): no DS op, no lgkmcnt.
// Lane 0 gets 0 (old operand), which is exactly the CTC halo boundary value.
__device__ __forceinline__ float shr1(float x) {
    return __int_as_float(__builtin_amdgcn_update_dpp(
        0, __float_as_int(x), 0x138 /*WAVE_SHR1*/, 0xf, 0xf, false));
}

// Fused kernel:
//   blocks [0, B)      : CTC forward, one 64-lane wave per batch element.
//                        Linear-prob domain, alpha in registers, 4-step
//                        halo-blocked wedge. Cross-lane halo + label-halo via
//                        DPP wave_shr1 (VALU — removes the per-group DS
//                        dependency chain; R2-R5's invariant ~300cyc/row was
//                        in-order DS completion + 4-bit lgkmcnt draining the
//                        prefetch queue at every halo/gvp consumer). Rows
//                        staged via 4-group-deep float4 register ring ->
//                        ds_write; label gathers issued TWO groups ahead of
//                        use from a 4-buffer LDS ring.
//   blocks [B, B+TRB)  : log + [B,T,C] -> [T,B,C] transpose (Output 0).
__global__ __launch_bounds__(64, 1) void ctc_fused(
    const float* __restrict__ yp,    // [B,T,C] probabilities
    const int*   __restrict__ yt,    // [B,L]
    const int*   __restrict__ il_,   // [B]
    const int*   __restrict__ ll_,   // [B]
    float* __restrict__ out_log,     // [T,B,C]
    float* __restrict__ out_loss)    // scalar, pre-zeroed; atomic mean
{
    if (blockIdx.x >= B) {
        // ---- transpose + log path (memory-bound, runs on idle CUs) ----
        int gid = (blockIdx.x - B) * 64 + threadIdx.x;
        const float4* in4 = (const float4*)yp;
        float4* o4 = (float4*)out_log;
        for (int i = gid; i < N4; i += TRB * 64) {
            int c4 = i & 31;
            int tb = i >> 5;
            int bb = tb & 63;
            int tt = tb >> 6;
            float4 v = in4[(bb * T + tt) * 32 + c4];
            float4 r;
            r.x = __logf(v.x); r.y = __logf(v.y);
            r.z = __logf(v.z); r.w = __logf(v.w);
            o4[i] = r;
        }
        return;
    }

    // ---- CTC forward path ----
    const int b    = blockIdx.x;
    const int lane = threadIdx.x;

    __shared__ float lsh[2048];   // four 4-row buffers (512 floats each)
    __shared__ float afin[S];     // final alphas for loss extraction

    int il = il_[b]; il = min(max(il, 1), T);
    int ll = ll_[b]; ll = min(max(ll, 1), L);
    const float* yb = yp + (size_t)b * T * C;   // [T,C] slice for this b

    // Labels. Lane owns states s = 8*lane-8+i in w[i], i in [0,16];
    // persistent alphas in w[8..16] (states 8l..8l+8), w[0..7] is the halo.
    int4 y4  = *(const int4*)(yt + b * L + 4 * lane);
    int  po  = lane ? 4 * lane - 4 : 0;
    int4 py4 = *(const int4*)(yt + b * L + po);              // prev lane's labels
    int  ppw = yt[b * L + (lane >= 2 ? 4 * lane - 5 : 0)];

    int lab[8]   = {py4.x, py4.y, py4.z, py4.w, y4.x, y4.y, y4.z, y4.w};
    int labm1[8] = {ppw,   py4.x, py4.y, py4.z, py4.w, y4.x, y4.y, y4.z};
    float skf[8];
    #pragma unroll
    for (int k = 0; k < 8; ++k)
        skf[k] = ((4 * lane + k >= 5) && (lab[k] != labm1[k])) ? 1.f : 0.f;

    const int c0 = y4.x, c1 = y4.y, c2 = y4.z, c3 = y4.w;  // own columns

    // Pair loader: pair m = rows (2m+1, 2m+2); lanes 0..31 carry the first
    // row, 32..63 the second; the wave reads 1KB fully coalesced.
    auto ldpair = [&](int m) -> float4 {
        int r = 2 * m + 1 + (lane >> 5);
        r = r > T - 1 ? T - 1 : r;
        return ((const float4*)(yb + (size_t)r * C))[lane & 31];
    };

    float p00 = yb[0];
    float p0l = yb[c0];

    // ---- warm-up ----
    float4 q0 = ldpair(0), q1 = ldpair(1);     // rows 1..4  -> buffer 0
    float4 q2 = ldpair(2), q3 = ldpair(3);     // rows 5..8  -> buffer 1
    float4 prr[8];                             // ring: pair m at slot m&7
    #pragma unroll
    for (int m = 4; m <= 11; ++m) prr[m & 7] = ldpair(m);   // rows 9..24

    ((float4*)(lsh +   0))[lane] = q0;
    ((float4*)(lsh + 256))[lane] = q1;
    ((float4*)(lsh + 512))[lane] = q2;
    ((float4*)(lsh + 768))[lane] = q3;

    // Gather rings: gv[q][j][*] = own-label probs of buffer q, row j;
    // gbv[q][j] = blank prob. Buffer q holds rows 4q+1..4q+4 (mod 16).
    float gv[4][4][4], gbv[4][4];
    #pragma unroll
    for (int q = 0; q < 2; ++q)
        #pragma unroll
        for (int j = 0; j < 4; ++j) {
            const float* base = lsh + q * 512 + j * 128;
            gbv[q][j] = base[0];
            gv[q][j][0] = base[c0]; gv[q][j][1] = base[c1];
            gv[q][j][2] = base[c2]; gv[q][j][3] = base[c3];
        }

    float w[17];
    #pragma unroll
    for (int i = 0; i < 17; ++i) w[i] = 0.f;
    if (lane == 0) { w[8] = p00; w[9] = p0l; }   // alpha0: states 0,1

    auto halo = [&]() {       // pure VALU (DPP), no DS
        #pragma unroll
        for (int k = 0; k < 8; ++k) w[k] = shr1(w[8 + k]);
    };
    halo();

    float ls = 0.f;        // accumulated log2 scale (exact integers)
    float m_meas = 1.0f;   // pipelined rescale max (lags ~8 steps)
    int t0 = 0;

    // One 4-step group: phase P = (t0>>2)&3, prr slot base S0 = (2P+4)&7.
    // Wedge consumes gv[P] (gathered 2 groups ago). Then: stage rows
    // t0+9..12 into buffer (P+2)&3, refill the ring (rows t0+25..28),
    // gather gv[(P+2)&3] (consumed 2 groups later), DPP halo.
    auto group = [&](auto Pc, auto S0c) {
        constexpr int P  = decltype(Pc)::value;
        constexpr int S0 = decltype(S0c)::value;
        constexpr int BF = (P + 2) & 3;
        // label-halo for this group's wedge: prev lane's own gathers (DPP).
        float g1[4], g2[4], g3[4];
        #pragma unroll
        for (int j = 0; j < 4; ++j) {
            g1[j] = shr1(gv[P][j][1]);
            g2[j] = shr1(gv[P][j][2]);
            g3[j] = shr1(gv[P][j][3]);
        }
        // wedge: 4 halo-blocked steps, in-place descending.
        #pragma unroll
        for (int j = 0; j < 4; ++j) {
            #pragma unroll
            for (int i = 16; i >= 2 * (j + 1); --i) {
                float acc = w[i] + w[i - 1];
                float g;
                if (i & 1) {
                    const int k = (i - 1) >> 1;
                    acc = fmaf(skf[k], w[i - 2], acc);
                    g = (k >= 4) ? gv[P][j][k - 4]
                                 : (k == 1 ? g1[j] : (k == 2 ? g2[j] : g3[j]));
                } else {
                    g = gbv[P][j];
                }
                w[i] = acc * g;
            }
        }
        // stage rows t0+9..12 (ring slots S0,S0+1; loaded 4 groups ago).
        ((float4*)(lsh + BF * 512      ))[lane] = prr[S0];
        ((float4*)(lsh + BF * 512 + 256))[lane] = prr[S0 + 1];
        prr[S0]     = ldpair((t0 >> 1) + 12);
        prr[S0 + 1] = ldpair((t0 >> 1) + 13);
        // gathers for group G+2 (2 full groups of slack before use).
        #pragma unroll
        for (int j = 0; j < 4; ++j) {
            const float* base = lsh + BF * 512 + j * 128;
            gbv[BF][j] = base[0];
            gv[BF][j][0] = base[c0]; gv[BF][j][1] = base[c1];
            gv[BF][j][2] = base[c2]; gv[BF][j][3] = base[c3];
        }
        halo();
        t0 += 4;
    };

    // Exact power-of-2 rescale, centered at 2^96.
    auto rescale = [&](float mm) {
        int eb = (__float_as_int(mm) >> 23) & 0xff;
        int sh = 350 - eb;
        sh = sh > 254 ? 254 : (sh < 1 ? 1 : sh);
        float inv = __int_as_float(sh << 23);
        #pragma unroll
        for (int i = 8; i < 17; ++i) w[i] *= inv;
        ls -= (float)(sh - 127);
    };
    auto maxw = [&]() {
        return fmaxf(fmaxf(fmaxf(w[8], w[9]), fmaxf(w[10], w[11])),
                     fmaxf(fmaxf(w[12], w[13]),
                           fmaxf(fmaxf(w[14], w[15]), w[16])));
    };

    const int full_end = ((il - 1) >> 2) << 2;

    // Main body: 4 groups (16 steps) per iteration; phases/slots static.
    while (t0 + 16 <= full_end) {
        float mm = m_meas;   // butterfly pipelined across 2 groups
        mm = fmaxf(mm, __shfl_xor(mm, 1));
        mm = fmaxf(mm, __shfl_xor(mm, 2));
        mm = fmaxf(mm, __shfl_xor(mm, 4));
        group(IC<0>{}, IC<4>{});
        mm = fmaxf(mm, __shfl_xor(mm, 8));
        mm = fmaxf(mm, __shfl_xor(mm, 16));
        mm = fmaxf(mm, __shfl_xor(mm, 32));
        group(IC<1>{}, IC<6>{});
        rescale(mm);
        m_meas = maxw();

        float m2 = m_meas;
        m2 = fmaxf(m2, __shfl_xor(m2, 1));
        m2 = fmaxf(m2, __shfl_xor(m2, 2));
        m2 = fmaxf(m2, __shfl_xor(m2, 4));
        group(IC<2>{}, IC<0>{});
        m2 = fmaxf(m2, __shfl_xor(m2, 8));
        m2 = fmaxf(m2, __shfl_xor(m2, 16));
        m2 = fmaxf(m2, __shfl_xor(m2, 32));
        group(IC<3>{}, IC<2>{});
        rescale(m2);
        m_meas = maxw();
    }

    // Peeled groups (0..3), each with a fresh (non-pipelined) rescale.
    auto fresh_rescale = [&]() {
        float mm = maxw();
        #pragma unroll
        for (int off = 1; off < 64; off <<= 1) mm = fmaxf(mm, __shfl_xor(mm, off));
        rescale(mm);
    };
    if (t0 + 4 <= full_end) { group(IC<0>{}, IC<4>{}); fresh_rescale(); }
    if (t0 + 4 <= full_end) { group(IC<1>{}, IC<6>{}); fresh_rescale(); }
    if (t0 + 4 <= full_end) { group(IC<2>{}, IC<0>{}); }

    // Tail: rows full_end+1 .. il-1 (0..3 steps) from gv[(full_end/4)&3].
    const int ph = (full_end >> 2) & 3;
    float tg[3][4], tb[3];
    switch (ph) {
    case 0:
        #pragma unroll
        for (int j = 0; j < 3; ++j) { tb[j]=gbv[0][j]; tg[j][0]=gv[0][j][0]; tg[j][1]=gv[0][j][1]; tg[j][2]=gv[0][j][2]; tg[j][3]=gv[0][j][3]; }
        break;
    case 1:
        #pragma unroll
        for (int j = 0; j < 3; ++j) { tb[j]=gbv[1][j]; tg[j][0]=gv[1][j][0]; tg[j][1]=gv[1][j][1]; tg[j][2]=gv[1][j][2]; tg[j][3]=gv[1][j][3]; }
        break;
    case 2:
        #pragma unroll
        for (int j = 0; j < 3; ++j) { tb[j]=gbv[2][j]; tg[j][0]=gv[2][j][0]; tg[j][1]=gv[2][j][1]; tg[j][2]=gv[2][j][2]; tg[j][3]=gv[2][j][3]; }
        break;
    default:
        #pragma unroll
        for (int j = 0; j < 3; ++j) { tb[j]=gbv[3][j]; tg[j][0]=gv[3][j][0]; tg[j][1]=gv[3][j][1]; tg[j][2]=gv[3][j][2]; tg[j][3]=gv[3][j][3]; }
        break;
    }
    #pragma unroll
    for (int j = 0; j < 3; ++j) {
        int r = full_end + 1 + j;
        if (r < il) {   // uniform branch (il, r wave-uniform)
            float hh = shr1(w[15]);
            float gb = tb[j];
            float n8  = (w[8] + hh) * gb;
            float n9  = fmaf(skf[4], hh,    w[9]  + w[8])  * tg[j][0];
            float n10 = (w[10] + w[9])  * gb;
            float n11 = fmaf(skf[5], w[9],  w[11] + w[10]) * tg[j][1];
            float n12 = (w[12] + w[11]) * gb;
            float n13 = fmaf(skf[6], w[11], w[13] + w[12]) * tg[j][2];
            float n14 = (w[14] + w[13]) * gb;
            float n15 = fmaf(skf[7], w[13], w[15] + w[14]) * tg[j][3];
            float n16 = (w[16] + w[15]) * gb;
            w[8] = n8;  w[9] = n9;  w[10] = n10; w[11] = n11; w[12] = n12;
            w[13] = n13; w[14] = n14; w[15] = n15; w[16] = n16;
        }
    }

    // Loss: -ln(alpha[2ll-1] + alpha[2ll]) with accumulated scale.
    #pragma unroll
    for (int k = 0; k < 8; ++k) afin[8 * lane + k] = w[8 + k];
    if (lane == 63) afin[512] = w[16];
    __syncthreads();
    if (lane == 0) {
        float e1 = afin[2 * ll - 1];
        float e2 = afin[2 * ll];
        float sum = fmaxf(e1 + e2, 1e-37f);
        float loss = -(__log2f(sum) + ls) * 0.6931471805599453f;  // nats
        atomicAdd(out_loss, loss * (1.0f / (float)B));
    }
}

extern "C" void kernel_launch(void* const* d_in, const int* in_sizes, int n_in,
                              void* d_out, int out_size, void* d_ws, size_t ws_size,
                              hipStream_t stream) {
    const int*   y_true = (const int*)d_in[0];
    const float* y_pred = (const float*)d_in[1];
    const int*   in_len = (const int*)d_in[2];
    const int*   lb_len = (const int*)d_in[3];

    float* out_log  = (float*)d_out;                      // [T,B,C]
    float* out_loss = (float*)d_out + (size_t)T * B * C;  // scalar

    hipMemsetAsync(out_loss, 0, sizeof(float), stream);
    ctc_fused<<<B + TRB, 64, 0, stream>>>(y_pred, y_true, in_len, lb_len,
                                          out_log, out_loss);
}

// Round 7
// 187.014 us; speedup vs baseline: 1.0765x; 1.0581x over previous
//
#include <hip/hip_runtime.h>
#include <math.h>

// Problem constants (from reference setup_inputs)
constexpr int B = 64;
constexpr int T = 1024;
constexpr int C = 128;
constexpr int L = 256;
constexpr int S = 2 * L + 1;     // 513 extended states
constexpr int TRB = 2048;        // transpose blocks (blockIdx >= B)

template <int N> struct IC { static constexpr int value = N; };

// shfl_up by 1 lane as pure VALU (DPP wave_shr:1): no DS op, no lgkmcnt.
// Lane 0 gets 0 (bound_ctrl=0 -> old operand = 0), the CTC halo boundary.
__device__ __forceinline__ float shr1(float x) {
    return __int_as_float(__builtin_amdgcn_update_dpp(
        0, __float_as_int(x), 0x138 /*WAVE_SHR1*/, 0xf, 0xf, false));
}

// One DPP max-combine stage: x = max(x, dpp_move(x, ctrl)). old = x so
// lanes with no source contribute x (harmless for max).
template <int CTRL>
__device__ __forceinline__ float maxdpp(float x) {
    float t = __int_as_float(__builtin_amdgcn_update_dpp(
        __float_as_int(x), __float_as_int(x), CTRL, 0xf, 0xf, false));
    return fmaxf(x, t);
}

// Wave64 max-reduce, result as wave-uniform SGPR float (readlane 63).
// row_shr:1/2/4/8 then row_bcast:15 (0x142), row_bcast:31 (0x143).
__device__ __forceinline__ float wave_max_dpp(float x) {
    x = maxdpp<0x111>(x);   // row_shr:1
    x = maxdpp<0x112>(x);   // row_shr:2
    x = maxdpp<0x114>(x);   // row_shr:4
    x = maxdpp<0x118>(x);   // row_shr:8
    x = maxdpp<0x142>(x);   // row_bcast:15
    x = maxdpp<0x143>(x);   // row_bcast:31
    return __int_as_float(__builtin_amdgcn_readlane(__float_as_int(x), 63));
}

// Fused kernel:
//   blocks [0, B)      : CTC forward, one 64-lane wave per batch element.
//                        Linear-prob domain, alpha in registers, 4-step
//                        halo-blocked wedge, DPP halos. Rescale max-reduce
//                        is now a pure-VALU DPP tree + readlane + scalar
//                        math (R2-R6's invariant ~300cyc/row: the shfl_xor
//                        butterflies were ds_swizzle chains, ~120cyc each
//                        dependent, exposed every 2 groups).
//   blocks [B, B+TRB)  : log + transpose, b-major CONTIGUOUS 16KB reads
//                        (old pattern read 512B bursts at 512KB stride ->
//                        DRAM page thrash; R1 measured it at ~840 GB/s).
__global__ __launch_bounds__(64, 1) void ctc_fused(
    const float* __restrict__ yp,    // [B,T,C] probabilities
    const int*   __restrict__ yt,    // [B,L]
    const int*   __restrict__ il_,   // [B]
    const int*   __restrict__ ll_,   // [B]
    float* __restrict__ out_log,     // [T,B,C]
    float* __restrict__ out_loss)    // scalar, pre-zeroed; atomic mean
{
    const int lane = threadIdx.x;
    if (blockIdx.x >= B) {
        // ---- transpose + log path: one b, 32 consecutive t-rows per block.
        int id = blockIdx.x - B;     // 0..2047
        int bb = id >> 5;            // batch element
        int ck = id & 31;            // which 32-row chunk of T
        const float4* src = (const float4*)yp + ((size_t)bb * T + ck * 32) * 32;
        float4* o4 = (float4*)out_log;
        #pragma unroll
        for (int k = 0; k < 16; ++k) {
            int o = k * 64 + lane;               // 0..1023 (contiguous read)
            float4 v = src[o];
            int tt = ck * 32 + (o >> 5);
            int c4 = o & 31;
            float4 r;
            r.x = __logf(v.x); r.y = __logf(v.y);
            r.z = __logf(v.z); r.w = __logf(v.w);
            o4[((size_t)tt * B + bb) * 32 + c4] = r;
        }
        return;
    }

    // ---- CTC forward path ----
    const int b = blockIdx.x;

    __shared__ float lsh[2048];   // four 4-row buffers (512 floats each)
    __shared__ float afin[S];     // final alphas for loss extraction

    int il = il_[b]; il = min(max(il, 1), T);
    int ll = ll_[b]; ll = min(max(ll, 1), L);
    const float* yb = yp + (size_t)b * T * C;   // [T,C] slice for this b

    // Labels. Lane owns states s = 8*lane-8+i in w[i], i in [0,16];
    // persistent alphas in w[8..16] (states 8l..8l+8), w[0..7] is the halo.
    int4 y4  = *(const int4*)(yt + b * L + 4 * lane);
    int  po  = lane ? 4 * lane - 4 : 0;
    int4 py4 = *(const int4*)(yt + b * L + po);              // prev lane's labels
    int  ppw = yt[b * L + (lane >= 2 ? 4 * lane - 5 : 0)];

    int lab[8]   = {py4.x, py4.y, py4.z, py4.w, y4.x, y4.y, y4.z, y4.w};
    int labm1[8] = {ppw,   py4.x, py4.y, py4.z, py4.w, y4.x, y4.y, y4.z};
    float skf[8];
    #pragma unroll
    for (int k = 0; k < 8; ++k)
        skf[k] = ((4 * lane + k >= 5) && (lab[k] != labm1[k])) ? 1.f : 0.f;

    const int c0 = y4.x, c1 = y4.y, c2 = y4.z, c3 = y4.w;  // own columns

    // Pair loader: pair m = rows (2m+1, 2m+2); lanes 0..31 carry the first
    // row, 32..63 the second; the wave reads 1KB fully coalesced.
    auto ldpair = [&](int m) -> float4 {
        int r = 2 * m + 1 + (lane >> 5);
        r = r > T - 1 ? T - 1 : r;
        return ((const float4*)(yb + (size_t)r * C))[lane & 31];
    };

    float p00 = yb[0];
    float p0l = yb[c0];

    // ---- warm-up ----
    float4 q0 = ldpair(0), q1 = ldpair(1);     // rows 1..4  -> buffer 0
    float4 q2 = ldpair(2), q3 = ldpair(3);     // rows 5..8  -> buffer 1
    float4 prr[8];                             // ring: pair m at slot m&7
    #pragma unroll
    for (int m = 4; m <= 11; ++m) prr[m & 7] = ldpair(m);   // rows 9..24

    ((float4*)(lsh +   0))[lane] = q0;
    ((float4*)(lsh + 256))[lane] = q1;
    ((float4*)(lsh + 512))[lane] = q2;
    ((float4*)(lsh + 768))[lane] = q3;

    // Gather rings: gv[q][j][*] = own-label probs of buffer q, row j;
    // gbv[q][j] = blank prob. Buffer q holds rows 4q+1..4q+4 (mod 16).
    float gv[4][4][4], gbv[4][4];
    #pragma unroll
    for (int q = 0; q < 2; ++q)
        #pragma unroll
        for (int j = 0; j < 4; ++j) {
            const float* base = lsh + q * 512 + j * 128;
            gbv[q][j] = base[0];
            gv[q][j][0] = base[c0]; gv[q][j][1] = base[c1];
            gv[q][j][2] = base[c2]; gv[q][j][3] = base[c3];
        }

    float w[17];
    #pragma unroll
    for (int i = 0; i < 17; ++i) w[i] = 0.f;
    if (lane == 0) { w[8] = p00; w[9] = p0l; }   // alpha0: states 0,1

    auto halo = [&]() {       // pure VALU (DPP), no DS
        #pragma unroll
        for (int k = 0; k < 8; ++k) w[k] = shr1(w[8 + k]);
    };
    halo();

    int lsi = 0;           // accumulated log2 scale (exact integer, scalar)
    int t0 = 0;

    // One 4-step group: phase P, prr slot base S0 (compile-time).
    auto group = [&](auto Pc, auto S0c) {
        constexpr int P  = decltype(Pc)::value;
        constexpr int S0 = decltype(S0c)::value;
        constexpr int BF = (P + 2) & 3;
        // label-halo for this group's wedge: prev lane's own gathers (DPP).
        float g1[4], g2[4], g3[4];
        #pragma unroll
        for (int j = 0; j < 4; ++j) {
            g1[j] = shr1(gv[P][j][1]);
            g2[j] = shr1(gv[P][j][2]);
            g3[j] = shr1(gv[P][j][3]);
        }
        // wedge: 4 halo-blocked steps, in-place descending.
        #pragma unroll
        for (int j = 0; j < 4; ++j) {
            #pragma unroll
            for (int i = 16; i >= 2 * (j + 1); --i) {
                float acc = w[i] + w[i - 1];
                float g;
                if (i & 1) {
                    const int k = (i - 1) >> 1;
                    acc = fmaf(skf[k], w[i - 2], acc);
                    g = (k >= 4) ? gv[P][j][k - 4]
                                 : (k == 1 ? g1[j] : (k == 2 ? g2[j] : g3[j]));
                } else {
                    g = gbv[P][j];
                }
                w[i] = acc * g;
            }
        }
        // stage rows t0+9..12 (ring slots S0,S0+1; loaded 4 groups ago).
        ((float4*)(lsh + BF * 512      ))[lane] = prr[S0];
        ((float4*)(lsh + BF * 512 + 256))[lane] = prr[S0 + 1];
        prr[S0]     = ldpair((t0 >> 1) + 12);
        prr[S0 + 1] = ldpair((t0 >> 1) + 13);
        // gathers for group G+2 (2 full groups of slack before use).
        #pragma unroll
        for (int j = 0; j < 4; ++j) {
            const float* base = lsh + BF * 512 + j * 128;
            gbv[BF][j] = base[0];
            gv[BF][j][0] = base[c0]; gv[BF][j][1] = base[c1];
            gv[BF][j][2] = base[c2]; gv[BF][j][3] = base[c3];
        }
        halo();
        t0 += 4;
    };

    auto maxw = [&]() {
        return fmaxf(fmaxf(fmaxf(w[8], w[9]), fmaxf(w[10], w[11])),
                     fmaxf(fmaxf(w[12], w[13]),
                           fmaxf(fmaxf(w[14], w[15]), w[16])));
    };
    // Fresh rescale: DPP tree max (VALU) -> scalar exponent math -> 9 muls.
    // Exact power-of-2 scale, centered at 2^96.
    auto rescale = [&]() {
        float mm = wave_max_dpp(maxw());
        int eb = (__float_as_int(mm) >> 23) & 0xff;
        int sh = 350 - eb;
        sh = sh > 254 ? 254 : (sh < 1 ? 1 : sh);
        float inv = __int_as_float(sh << 23);
        #pragma unroll
        for (int i = 8; i < 17; ++i) w[i] *= inv;
        lsi -= sh - 127;
    };

    const int full_end = ((il - 1) >> 2) << 2;

    // Main body: 4 groups (16 steps) per iteration; phases/slots static.
    while (t0 + 16 <= full_end) {
        group(IC<0>{}, IC<4>{});
        group(IC<1>{}, IC<6>{});
        rescale();
        group(IC<2>{}, IC<0>{});
        group(IC<3>{}, IC<2>{});
        rescale();
    }

    // Peeled groups (0..3).
    if (t0 + 4 <= full_end) { group(IC<0>{}, IC<4>{}); rescale(); }
    if (t0 + 4 <= full_end) { group(IC<1>{}, IC<6>{}); rescale(); }
    if (t0 + 4 <= full_end) { group(IC<2>{}, IC<0>{}); }

    // Tail: rows full_end+1 .. il-1 (0..3 steps) from gv[(full_end/4)&3].
    const int ph = (full_end >> 2) & 3;
    float tg[3][4], tb[3];
    switch (ph) {
    case 0:
        #pragma unroll
        for (int j = 0; j < 3; ++j) { tb[j]=gbv[0][j]; tg[j][0]=gv[0][j][0]; tg[j][1]=gv[0][j][1]; tg[j][2]=gv[0][j][2]; tg[j][3]=gv[0][j][3]; }
        break;
    case 1:
        #pragma unroll
        for (int j = 0; j < 3; ++j) { tb[j]=gbv[1][j]; tg[j][0]=gv[1][j][0]; tg[j][1]=gv[1][j][1]; tg[j][2]=gv[1][j][2]; tg[j][3]=gv[1][j][3]; }
        break;
    case 2:
        #pragma unroll
        for (int j = 0; j < 3; ++j) { tb[j]=gbv[2][j]; tg[j][0]=gv[2][j][0]; tg[j][1]=gv[2][j][1]; tg[j][2]=gv[2][j][2]; tg[j][3]=gv[2][j][3]; }
        break;
    default:
        #pragma unroll
        for (int j = 0; j < 3; ++j) { tb[j]=gbv[3][j]; tg[j][0]=gv[3][j][0]; tg[j][1]=gv[3][j][1]; tg[j][2]=gv[3][j][2]; tg[j][3]=gv[3][j][3]; }
        break;
    }
    #pragma unroll
    for (int j = 0; j < 3; ++j) {
        int r = full_end + 1 + j;
        if (r < il) {   // uniform branch (il, r wave-uniform)
            float hh = shr1(w[15]);
            float gb = tb[j];
            float n8  = (w[8] + hh) * gb;
            float n9  = fmaf(skf[4], hh,    w[9]  + w[8])  * tg[j][0];
            float n10 = (w[10] + w[9])  * gb;
            float n11 = fmaf(skf[5], w[9],  w[11] + w[10]) * tg[j][1];
            float n12 = (w[12] + w[11]) * gb;
            float n13 = fmaf(skf[6], w[11], w[13] + w[12]) * tg[j][2];
            float n14 = (w[14] + w[13]) * gb;
            float n15 = fmaf(skf[7], w[13], w[15] + w[14]) * tg[j][3];
            float n16 = (w[16] + w[15]) * gb;
            w[8] = n8;  w[9] = n9;  w[10] = n10; w[11] = n11; w[12] = n12;
            w[13] = n13; w[14] = n14; w[15] = n15; w[16] = n16;
        }
    }

    // Loss: -ln(alpha[2ll-1] + alpha[2ll]) with accumulated scale.
    #pragma unroll
    for (int k = 0; k < 8; ++k) afin[8 * lane + k] = w[8 + k];
    if (lane == 63) afin[512] = w[16];
    __syncthreads();
    if (lane == 0) {
        float e1 = afin[2 * ll - 1];
        float e2 = afin[2 * ll];
        float sum = fmaxf(e1 + e2, 1e-37f);
        float loss = -(__log2f(sum) + (float)lsi) * 0.6931471805599453f;  // nats
        atomicAdd(out_loss, loss * (1.0f / (float)B));
    }
}

extern "C" void kernel_launch(void* const* d_in, const int* in_sizes, int n_in,
                              void* d_out, int out_size, void* d_ws, size_t ws_size,
                              hipStream_t stream) {
    const int*   y_true = (const int*)d_in[0];
    const float* y_pred = (const float*)d_in[1];
    const int*   in_len = (const int*)d_in[2];
    const int*   lb_len = (const int*)d_in[3];

    float* out_log  = (float*)d_out;                      // [T,B,C]
    float* out_loss = (float*)d_out + (size_t)T * B * C;  // scalar

    hipMemsetAsync(out_loss, 0, sizeof(float), stream);
    ctc_fused<<<B + TRB, 64, 0, stream>>>(y_pred, y_true, in_len, lb_len,
                                          out_log, out_loss);
}